// Round 16
// baseline (80.121 us; speedup 1.0000x reference)
//
#include <hip/hip_runtime.h>
#include <stdint.h>

#define BATCH   16384
#define NUM_NUM 32
#define NUM_CAT 32
#define CARD    128
#define OUT_F   32
#define XSTRIDE 4128   // NUM_NUM + NUM_CAT*CARD
#define OSTRIDE 1056   // NUM_NUM + NUM_CAT*OUT_F

typedef __attribute__((ext_vector_type(8))) short short8;  // 8 bf16 (4 VGPRs)
typedef __attribute__((ext_vector_type(4))) float f32x4;

// f32 -> bf16, round-to-nearest-even, pure bit ops (r15-proven, absmax 0.031).
__device__ __forceinline__ unsigned short f2bf(float f) {
    unsigned u = __builtin_bit_cast(unsigned, f);
    return (unsigned short)((u + 0x7FFFu + ((u >> 16) & 1u)) >> 16);
}

// r15 MFMA formulation + explicit 1-deep m-tile pipeline (ping-pong v[2][8],
// statically indexed after full unroll - rule-20 safe). Loads for tile m+1
// issue BEFORE cvt/MFMA of tile m -> compiler emits counted vmcnt (not drain);
// 4 waves/SIMD TLP covers the residual latency. No LDS, no barriers.
// Fragments (HW-verified m89/m91): A lane l = A[row=l&15][k=(l>>4)*8+i];
// B lane l = B[k=(l>>4)*8+i][col=l&15]; D col=l&15, row=(l>>4)*4+reg.
// VGPR ~120 < 128 cap @(256,4). Spill signature = WRITE_SIZE >> 68MB (r4).
__global__ __launch_bounds__(256, 4) void emb_mfma(const float* __restrict__ x,
                                                   const float* __restrict__ Wm,
                                                   const float* __restrict__ bias,
                                                   float* __restrict__ out) {
    const int f    = blockIdx.x;
    const int row0 = blockIdx.y * 256;
    const int tid  = threadIdx.x;
    const int l    = tid & 63;
    const int wv   = tid >> 6;
    const int lr   = l & 15;   // A-row / B-col / D-col
    const int lg   = l >> 4;   // k-group (8 elems each)

    // ---- B fragments: W[f] -> bf16 VGPRs, 2 n-tiles x 4 k-frags (one-time) ----
    const float* wf = Wm + (size_t)f * (CARD * OUT_F);
    short8 bw[2][4];
#pragma unroll
    for (int n = 0; n < 2; ++n)
#pragma unroll
        for (int kf = 0; kf < 4; ++kf)
#pragma unroll
            for (int i = 0; i < 8; ++i)
                bw[n][kf][i] = (short)f2bf(wf[(kf * 32 + lg * 8 + i) * OUT_F + n * 16 + lr]);

    const float bias0 = bias[f * OUT_F + lr];
    const float bias1 = bias[f * OUT_F + 16 + lr];

    const float* xf    = x + NUM_NUM + f * CARD;
    float*       obase = out + NUM_NUM + f * OUT_F;
    const int    wrow  = row0 + wv * 64;

    float4 v[2][8];  // ping-pong staging; all indices compile-time after unroll

    // prologue: load m-tile 0
    {
        const float* xr = xf + (size_t)(wrow + lr) * XSTRIDE;
#pragma unroll
        for (int kf = 0; kf < 4; ++kf) {
            v[0][kf * 2]     = *(const float4*)(xr + kf * 32 + lg * 8);
            v[0][kf * 2 + 1] = *(const float4*)(xr + kf * 32 + lg * 8 + 4);
        }
    }

#pragma unroll
    for (int m = 0; m < 4; ++m) {
        // issue next tile's loads first (in-flight across this tile's cvt+MFMA)
        if (m < 3) {
            const float* xr = xf + (size_t)(wrow + (m + 1) * 16 + lr) * XSTRIDE;
#pragma unroll
            for (int kf = 0; kf < 4; ++kf) {
                v[(m + 1) & 1][kf * 2]     = *(const float4*)(xr + kf * 32 + lg * 8);
                v[(m + 1) & 1][kf * 2 + 1] = *(const float4*)(xr + kf * 32 + lg * 8 + 4);
            }
        }

        f32x4 acc0 = {0.f, 0.f, 0.f, 0.f};
        f32x4 acc1 = {0.f, 0.f, 0.f, 0.f};
#pragma unroll
        for (int kf = 0; kf < 4; ++kf) {
            const float4 v0 = v[m & 1][kf * 2];
            const float4 v1 = v[m & 1][kf * 2 + 1];
            short8       af;
            af[0] = (short)f2bf(v0.x); af[1] = (short)f2bf(v0.y);
            af[2] = (short)f2bf(v0.z); af[3] = (short)f2bf(v0.w);
            af[4] = (short)f2bf(v1.x); af[5] = (short)f2bf(v1.y);
            af[6] = (short)f2bf(v1.z); af[7] = (short)f2bf(v1.w);
            acc0 = __builtin_amdgcn_mfma_f32_16x16x32_bf16(af, bw[0][kf], acc0, 0, 0, 0);
            acc1 = __builtin_amdgcn_mfma_f32_16x16x32_bf16(af, bw[1][kf], acc1, 0, 0, 0);
        }

        // D: row = (l>>4)*4 + r, col = lr; 16-lane-consecutive dwords -> 64B segs
#pragma unroll
        for (int r = 0; r < 4; ++r) {
            const size_t orow = (size_t)(wrow + m * 16 + lg * 4 + r) * OSTRIDE;
            obase[orow + lr]      = acc0[r] + bias0;
            obase[orow + 16 + lr] = acc1[r] + bias1;
        }
    }

    // ---- numeric passthrough: one block per stripe (f == stripe&31), row/thread ----
    if (f == (blockIdx.y & 31)) {
        const float4* src = (const float4*)(x + (size_t)(row0 + tid) * XSTRIDE);
        float4*       dst = (float4*)(out + (size_t)(row0 + tid) * OSTRIDE);
#pragma unroll
        for (int q = 0; q < 8; ++q) dst[q] = src[q];
    }
}

extern "C" void kernel_launch(void* const* d_in, const int* in_sizes, int n_in,
                              void* d_out, int out_size, void* d_ws, size_t ws_size,
                              hipStream_t stream) {
    const float* x    = (const float*)d_in[0];
    const float* W    = (const float*)d_in[1];
    const float* bias = (const float*)d_in[2];
    float*       out  = (float*)d_out;

    dim3 grid(NUM_CAT, BATCH / 256);  // (32, 64), f fastest
    emb_mfma<<<grid, 256, 0, stream>>>(x, W, bias, out);
}